// Round 2
// baseline (131.864 us; speedup 1.0000x reference)
//
#include <hip/hip_runtime.h>
#include <hip/hip_bf16.h>

#define NB 64
#define CD 128
#define LL 4096
#define LCHUNK 64
#define NSUB 4
#define P1_NBLK 16     // LL/(LCHUNK*NSUB)
#define NCHUNK 64      // LL/LCHUNK

typedef __attribute__((ext_vector_type(8))) short short8;
typedef __attribute__((ext_vector_type(4))) float f32x4;

#define LOG2E 1.4426950408889634f

// ws layout (bytes)
#define WT_OFF   0                                 // 3*128*128 bf16 = 98304 B
#define WSM_OFF  131072
#define WSS_OFF  (WSM_OFF + NB*P1_NBLK*CD*4)
#define WSP_OFF  (WSS_OFF + NB*P1_NBLK*CD*4)
#define POOL_OFF (WSP_OFF + NB*P1_NBLK*CD*4)
#define WSQ_OFF  (8u*1024u*1024u)                  // 64 n * 64 chunk * 128 d * 64 l bf16 = 64 MB

__device__ __forceinline__ unsigned short f2bf(float f) {
    union { float f; unsigned u; } v; v.f = f;
    unsigned r = v.u + 0x7FFFu + ((v.u >> 16) & 1u);
    return (unsigned short)(r >> 16);
}
__device__ __forceinline__ float bf2f(unsigned short h) {
    union { unsigned u; float f; } v; v.u = ((unsigned)h) << 16;
    return v.f;
}

// W[t] is [C=128][D=128]; produce wt[t][d][c] = bf16(W[c][d])  (i.e. W^T, c contiguous)
__global__ void prep_wt(const float* __restrict__ Wq, const float* __restrict__ Wk,
                        const float* __restrict__ Wv, unsigned short* __restrict__ wt) {
    int t = blockIdx.x >> 7;
    int d = blockIdx.x & 127;
    const float* W = (t == 0) ? Wq : (t == 1) ? Wk : Wv;
    int c = threadIdx.x;
    wt[((size_t)t*CD + d)*CD + c] = f2bf(W[c*CD + d]);
}

// ---- pass 1: fused Q,K,V GEMM; in-lane online-softmax partials; sig(Q) -> ws (bf16) ----
__global__ __launch_bounds__(256, 2)
void aft_pass1(const float* __restrict__ x, const unsigned short* __restrict__ wt,
               const float* __restrict__ bq, const float* __restrict__ bk,
               const float* __restrict__ bv,
               float* __restrict__ wsM, float* __restrict__ wsS, float* __restrict__ wsP,
               unsigned short* __restrict__ wsq) {
    __shared__ unsigned short lds_x[LCHUNK * 136];   // [l][c], c padded
    __shared__ unsigned short lds_q[CD * 68];        // [d][l'], l' padded
    const int tid = threadIdx.x;
    const int n = blockIdx.x >> 4;
    const int blk = blockIdx.x & 15;
    const int w = tid >> 6, lane = tid & 63, r = lane & 15, g = lane >> 4;

    // A fragments: lane holds W^T[d = 32w+16rt+r][c = 32*s + 8*g .. +7]
    short8 a_q[2][4], a_k[2][4], a_v[2][4];
#pragma unroll
    for (int rt = 0; rt < 2; ++rt)
#pragma unroll
        for (int s = 0; s < 4; ++s) {
            int d = 32*w + 16*rt + r;
            a_q[rt][s] = *(const short8*)(wt + ((size_t)(0*CD + d))*CD + 32*s + 8*g);
            a_k[rt][s] = *(const short8*)(wt + ((size_t)(1*CD + d))*CD + 32*s + 8*g);
            a_v[rt][s] = *(const short8*)(wt + ((size_t)(2*CD + d))*CD + 32*s + 8*g);
        }

    f32x4 bqv[2], bkv[2], bvv[2];
#pragma unroll
    for (int rt = 0; rt < 2; ++rt) {
        bqv[rt] = *(const f32x4*)(bq + 32*w + 16*rt + 4*g);
        bkv[rt] = *(const f32x4*)(bk + 32*w + 16*rt + 4*g);
        bvv[rt] = *(const f32x4*)(bv + 32*w + 16*rt + 4*g);
    }

    // per-lane online-softmax state (exp2 domain), over this lane's own l subset
    float m_run[2][4], s_run[2][4], p_run[2][4];
#pragma unroll
    for (int rt = 0; rt < 2; ++rt)
#pragma unroll
        for (int v = 0; v < 4; ++v) { m_run[rt][v] = -1e30f; s_run[rt][v] = 0.f; p_run[rt][v] = 0.f; }

    for (int sub = 0; sub < NSUB; ++sub) {
        const int ch = blk*NSUB + sub;
        const int l0 = ch * LCHUNK;
        __syncthreads();
        // stage X[n][:, l0:l0+64] -> LDS transposed bf16
        {
            const int cc = tid >> 4, f = tid & 15;
#pragma unroll
            for (int it = 0; it < 8; ++it) {
                int c = cc + 16*it;
                f32x4 xv = *(const f32x4*)(x + ((size_t)n*CD + c)*LL + l0 + 4*f);
                int l = 4*f;
                lds_x[(l+0)*136 + c] = f2bf(xv[0]);
                lds_x[(l+1)*136 + c] = f2bf(xv[1]);
                lds_x[(l+2)*136 + c] = f2bf(xv[2]);
                lds_x[(l+3)*136 + c] = f2bf(xv[3]);
            }
        }
        __syncthreads();

#pragma unroll
        for (int ct = 0; ct < 4; ++ct) {
            f32x4 aq[2], ak[2], av[2];
#pragma unroll
            for (int rt = 0; rt < 2; ++rt) {
                aq[rt] = (f32x4){0.f,0.f,0.f,0.f};
                ak[rt] = (f32x4){0.f,0.f,0.f,0.f};
                av[rt] = (f32x4){0.f,0.f,0.f,0.f};
            }
#pragma unroll
            for (int s = 0; s < 4; ++s) {
                short8 b = *(const short8*)(lds_x + (ct*16 + r)*136 + 32*s + 8*g);
                aq[0] = __builtin_amdgcn_mfma_f32_16x16x32_bf16(a_q[0][s], b, aq[0], 0,0,0);
                aq[1] = __builtin_amdgcn_mfma_f32_16x16x32_bf16(a_q[1][s], b, aq[1], 0,0,0);
                ak[0] = __builtin_amdgcn_mfma_f32_16x16x32_bf16(a_k[0][s], b, ak[0], 0,0,0);
                ak[1] = __builtin_amdgcn_mfma_f32_16x16x32_bf16(a_k[1][s], b, ak[1], 0,0,0);
                av[0] = __builtin_amdgcn_mfma_f32_16x16x32_bf16(a_v[0][s], b, av[0], 0,0,0);
                av[1] = __builtin_amdgcn_mfma_f32_16x16x32_bf16(a_v[1][s], b, av[1], 0,0,0);
            }
            // in-lane online update (one l per (rt,v): l = l0 + 16ct + r)
#pragma unroll
            for (int rt = 0; rt < 2; ++rt)
#pragma unroll
                for (int v = 0; v < 4; ++v) {
                    float k2 = (ak[rt][v] + bkv[rt][v]) * LOG2E;
                    float vv = av[rt][v] + bvv[rt][v];
                    float mo = m_run[rt][v];
                    float mn = fmaxf(mo, k2);
                    float sc = __builtin_amdgcn_exp2f(mo - mn);
                    float e  = __builtin_amdgcn_exp2f(k2 - mn);
                    s_run[rt][v] = s_run[rt][v]*sc + e;
                    p_run[rt][v] = p_run[rt][v]*sc + e*vv;
                    m_run[rt][v] = mn;
                    // sigmoid(q) -> bf16 -> LDS transpose buffer
                    float q2 = (aq[rt][v] + bqv[rt][v]) * LOG2E;
                    float sg = __builtin_amdgcn_rcpf(1.f + __builtin_amdgcn_exp2f(-q2));
                    lds_q[(32*w + 16*rt + 4*g + v)*68 + ct*16 + r] = f2bf(sg);
                }
        }
        __syncthreads();
        // store sig(Q) tile: ws layout [n][ch][d][64] bf16, fully coalesced
        {
            unsigned short* tile = wsq + ((size_t)(n*NCHUNK + ch)) * (CD*LCHUNK);
            const int col = tid & 7;
#pragma unroll
            for (int it = 0; it < 4; ++it) {
                int row = (tid >> 3) + 32*it;
                short8 val = *(const short8*)(lds_q + row*68 + 8*col);
                *(short8*)(tile + row*LCHUNK + 8*col) = val;
            }
        }
    }

    // cross-lane merge over the 16 r-lanes (masks 1,2,4,8)
#pragma unroll
    for (int rt = 0; rt < 2; ++rt)
#pragma unroll
        for (int v = 0; v < 4; ++v) {
            float m = m_run[rt][v], s = s_run[rt][v], p = p_run[rt][v];
#pragma unroll
            for (int mask = 1; mask <= 8; mask <<= 1) {
                float om = __shfl_xor(m, mask, 64);
                float os = __shfl_xor(s, mask, 64);
                float op = __shfl_xor(p, mask, 64);
                float mn = fmaxf(m, om);
                float sc1 = __builtin_amdgcn_exp2f(m - mn);
                float sc2 = __builtin_amdgcn_exp2f(om - mn);
                s = s*sc1 + os*sc2;
                p = p*sc1 + op*sc2;
                m = mn;
            }
            m_run[rt][v] = m; s_run[rt][v] = s; p_run[rt][v] = p;
        }

    if (r == 0) {
#pragma unroll
        for (int rt = 0; rt < 2; ++rt)
#pragma unroll
            for (int v = 0; v < 4; ++v) {
                int d = 32*w + 16*rt + 4*g + v;
                size_t idx = ((size_t)n*P1_NBLK + blk)*CD + d;
                wsM[idx] = m_run[rt][v];
                wsS[idx] = s_run[rt][v];
                wsP[idx] = p_run[rt][v];
            }
    }
}

// ---------------- pass 2: combine partials -> pooled[n][d] ----------------
__global__ void aft_pass2(const float* __restrict__ wsM, const float* __restrict__ wsS,
                          const float* __restrict__ wsP, float* __restrict__ pooled) {
    int n = blockIdx.x, d = threadIdx.x;
    float m = -1e30f, s = 0.f, p = 0.f;
    for (int b = 0; b < P1_NBLK; ++b) {
        size_t idx = ((size_t)n*P1_NBLK + b)*CD + d;
        float mb = wsM[idx], sb = wsS[idx], pb = wsP[idx];
        float mn = fmaxf(m, mb);
        float au = __builtin_amdgcn_exp2f(m - mn);
        float bu = __builtin_amdgcn_exp2f(mb - mn);
        s = s*au + sb*bu;
        p = p*au + pb*bu;
        m = mn;
    }
    pooled[(size_t)n*CD + d] = p / s;
}

// ---------------- pass 3: out[n][d][l] = sig_q * pooled[n][d], pure streaming ----------------
__global__ __launch_bounds__(256)
void aft_pass3(const unsigned short* __restrict__ wsq, const float* __restrict__ pooled,
               float* __restrict__ out) {
    __shared__ float lpool[CD];
    const int n = blockIdx.x >> 6;
    const int ch = blockIdx.x & 63;
    if (threadIdx.x < CD) lpool[threadIdx.x] = pooled[(size_t)n*CD + threadIdx.x];
    __syncthreads();
    const unsigned short* tile = wsq + ((size_t)(n*NCHUNK + ch)) * (CD*LCHUNK);
    const int l0 = ch * LCHUNK;
#pragma unroll
    for (int it = 0; it < 4; ++it) {
        int gi = threadIdx.x + 256*it;         // 0..1023
        int row = gi >> 3, col = gi & 7;
        short8 v = *(const short8*)(tile + row*LCHUNK + 8*col);
        float pl = lpool[row];
        f32x4 o0, o1;
#pragma unroll
        for (int j = 0; j < 4; ++j) {
            o0[j] = bf2f((unsigned short)v[j]) * pl;
            o1[j] = bf2f((unsigned short)v[4+j]) * pl;
        }
        float* dst = out + ((size_t)n*CD + row)*LL + l0 + 8*col;
        *(f32x4*)dst = o0;
        *(f32x4*)(dst + 4) = o1;
    }
}

extern "C" void kernel_launch(void* const* d_in, const int* in_sizes, int n_in,
                              void* d_out, int out_size, void* d_ws, size_t ws_size,
                              hipStream_t stream) {
    const float* x  = (const float*)d_in[0];
    const float* Wq = (const float*)d_in[1];
    const float* bq = (const float*)d_in[2];
    const float* Wk = (const float*)d_in[3];
    const float* bk = (const float*)d_in[4];
    const float* Wv = (const float*)d_in[5];
    const float* bv = (const float*)d_in[6];
    float* out = (float*)d_out;
    char* ws = (char*)d_ws;
    unsigned short* wt = (unsigned short*)(ws + WT_OFF);
    float* wsM = (float*)(ws + WSM_OFF);
    float* wsS = (float*)(ws + WSS_OFF);
    float* wsP = (float*)(ws + WSP_OFF);
    float* pooled = (float*)(ws + POOL_OFF);
    unsigned short* wsq = (unsigned short*)(ws + WSQ_OFF);

    prep_wt<<<384, 128, 0, stream>>>(Wq, Wk, Wv, wt);
    aft_pass1<<<NB * P1_NBLK, 256, 0, stream>>>(x, wt, bq, bk, bv, wsM, wsS, wsP, wsq);
    aft_pass2<<<NB, CD, 0, stream>>>(wsM, wsS, wsP, pooled);
    aft_pass3<<<NB * NCHUNK, 256, 0, stream>>>(wsq, pooled, out);
}

// Round 3
// 122.108 us; speedup vs baseline: 1.0799x; 1.0799x over previous
//
#include <hip/hip_runtime.h>
#include <hip/hip_bf16.h>

#define NB 64
#define CD 128
#define LL 4096
#define LCHUNK 64
#define NCHUNK 64      // LL/LCHUNK

typedef __attribute__((ext_vector_type(8))) short short8;
typedef __attribute__((ext_vector_type(4))) float f32x4;

#define LOG2E 1.4426950408889634f

// ws layout (bytes)
#define WT_OFF   0                                  // 3*128*128 bf16 = 96 KB
#define WSS_OFF  (1u<<20)                           // 64*64*128 f32 = 2 MB
#define WSP_OFF  ((1u<<20) + NB*NCHUNK*CD*4)
#define POOL_OFF ((1u<<20) + 2u*NB*NCHUNK*CD*4)
#define WSQ_OFF  (8u<<20)                           // 64 MB bf16 sig(q)

__device__ __forceinline__ unsigned short f2bf(float f) {
    union { float f; unsigned u; } v; v.f = f;
    unsigned r = v.u + 0x7FFFu + ((v.u >> 16) & 1u);
    return (unsigned short)(r >> 16);
}
__device__ __forceinline__ float bf2f(unsigned short h) {
    union { unsigned u; float f; } v; v.u = ((unsigned)h) << 16;
    return v.f;
}
__device__ __forceinline__ unsigned pack2(float lo, float hi) {
    union { __hip_bfloat162 h; unsigned u; } v;
    v.h = __float22bfloat162_rn(float2{lo, hi});   // v_cvt_pk_bf16_f32
    return v.u;
}

// W[t] is [C=128][D=128]; produce wt[t][d][c] = bf16(W[c][d])
__global__ void prep_wt(const float* __restrict__ Wq, const float* __restrict__ Wk,
                        const float* __restrict__ Wv, unsigned short* __restrict__ wt) {
    int t = blockIdx.x >> 7;
    int d = blockIdx.x & 127;
    const float* W = (t == 0) ? Wq : (t == 1) ? Wk : Wv;
    int c = threadIdx.x;
    wt[((size_t)t*CD + d)*CD + c] = f2bf(W[c*CD + d]);
}

// ---- pass 1: fused Q,K,V GEMM on one 64-l chunk; (s,p) partials; sig(Q)->ws ----
// LDS x layout: element (l,c) at byte 272*l + 16*((c>>3) ^ ((l>>2)&7)) + (c&7)*2
__global__ __launch_bounds__(256, 4)
void aft_pass1(const float* __restrict__ x, const unsigned short* __restrict__ wt,
               const float* __restrict__ bq, const float* __restrict__ bk,
               const float* __restrict__ bv,
               float* __restrict__ wsS, float* __restrict__ wsP,
               unsigned short* __restrict__ wsq) {
    __shared__ char lds_x[64 * 272];                 // 17408 B, swizzled
    __shared__ unsigned short lds_q[CD * 68];        // [d][l'] transpose buffer
    const int tid = threadIdx.x;
    const int n = blockIdx.x >> 6;
    const int ch = blockIdx.x & 63;
    const int l0 = ch * LCHUNK;
    const int w = tid >> 6, lane = tid & 63, r = lane & 15, g = lane >> 4;

    // ---- stage x[n][:, l0:l0+64] -> swizzled LDS bf16 (conflict-free u32 writes) ----
    {
        const int f = tid & 15;          // l-quad: rows l = 4f..4f+3
        const int tg = tid >> 4;         // 0..15 -> c-pair group
        const int sw = 16 * 272 * 0 + 0; (void)sw;
#pragma unroll
        for (int it = 0; it < 4; ++it) {
            int cp = tg + 16*it;         // c pair index 0..63
            int c0 = 2*cp;
            f32x4 lo = *(const f32x4*)(x + ((size_t)n*CD + c0    )*LL + l0 + 4*f);
            f32x4 hi = *(const f32x4*)(x + ((size_t)n*CD + c0 + 1)*LL + l0 + 4*f);
            int B  = cp >> 2;            // 16B block index 0..15
            int go = cp & 3;             // dword within block
            char* base = lds_x + (4*f)*272 + 16*(B ^ (f & 7)) + 4*go;
#pragma unroll
            for (int j = 0; j < 4; ++j)
                *(unsigned*)(base + j*272) = pack2(lo[j], hi[j]);
        }
    }

    // K,V A-fragments: lane holds wt[mat][d=32w+16rt+r][c=32s+8g..+7]
    short8 a_k[2][4], a_v[2][4];
#pragma unroll
    for (int rt = 0; rt < 2; ++rt)
#pragma unroll
        for (int s = 0; s < 4; ++s) {
            int d = 32*w + 16*rt + r;
            a_k[rt][s] = *(const short8*)(wt + ((size_t)(1*CD + d))*CD + 32*s + 8*g);
            a_v[rt][s] = *(const short8*)(wt + ((size_t)(2*CD + d))*CD + 32*s + 8*g);
        }
    f32x4 bkv[2], bvv[2];
#pragma unroll
    for (int rt = 0; rt < 2; ++rt) {
        bkv[rt] = *(const f32x4*)(bk + 32*w + 16*rt + 4*g);
        bvv[rt] = *(const f32x4*)(bv + 32*w + 16*rt + 4*g);
    }

    __syncthreads();

    float s_run[2][4], p_run[2][4];
#pragma unroll
    for (int rt = 0; rt < 2; ++rt)
#pragma unroll
        for (int v = 0; v < 4; ++v) { s_run[rt][v] = 0.f; p_run[rt][v] = 0.f; }

    // ---- K,V GEMM + per-lane (s,p) accumulation ----
#pragma unroll 1
    for (int ct = 0; ct < 4; ++ct) {
        f32x4 ak[2], av[2];
#pragma unroll
        for (int rt = 0; rt < 2; ++rt) {
            ak[rt] = (f32x4){0.f,0.f,0.f,0.f};
            av[rt] = (f32x4){0.f,0.f,0.f,0.f};
        }
        const int lrow = 16*ct + r;
        const int lsw = (lrow >> 2) & 7;
#pragma unroll
        for (int s = 0; s < 4; ++s) {
            const short8 b = *(const short8*)(lds_x + lrow*272 + 16*((4*s + g) ^ lsw));
            ak[0] = __builtin_amdgcn_mfma_f32_16x16x32_bf16(a_k[0][s], b, ak[0], 0,0,0);
            ak[1] = __builtin_amdgcn_mfma_f32_16x16x32_bf16(a_k[1][s], b, ak[1], 0,0,0);
            av[0] = __builtin_amdgcn_mfma_f32_16x16x32_bf16(a_v[0][s], b, av[0], 0,0,0);
            av[1] = __builtin_amdgcn_mfma_f32_16x16x32_bf16(a_v[1][s], b, av[1], 0,0,0);
        }
#pragma unroll
        for (int rt = 0; rt < 2; ++rt)
#pragma unroll
            for (int v = 0; v < 4; ++v) {
                float e = __builtin_amdgcn_exp2f((ak[rt][v] + bkv[rt][v]) * LOG2E);
                s_run[rt][v] += e;
                p_run[rt][v] += e * (av[rt][v] + bvv[rt][v]);
            }
    }

    // ---- Q GEMM (reuses registers of a_k/a_v) + sigmoid -> lds_q ----
    short8 a_q[2][4];
#pragma unroll
    for (int rt = 0; rt < 2; ++rt)
#pragma unroll
        for (int s = 0; s < 4; ++s) {
            int d = 32*w + 16*rt + r;
            a_q[rt][s] = *(const short8*)(wt + ((size_t)(0*CD + d))*CD + 32*s + 8*g);
        }
    f32x4 bqv[2];
#pragma unroll
    for (int rt = 0; rt < 2; ++rt)
        bqv[rt] = *(const f32x4*)(bq + 32*w + 16*rt + 4*g);

#pragma unroll 1
    for (int ct = 0; ct < 4; ++ct) {
        f32x4 aq[2];
        aq[0] = (f32x4){0.f,0.f,0.f,0.f};
        aq[1] = (f32x4){0.f,0.f,0.f,0.f};
        const int lrow = 16*ct + r;
        const int lsw = (lrow >> 2) & 7;
#pragma unroll
        for (int s = 0; s < 4; ++s) {
            const short8 b = *(const short8*)(lds_x + lrow*272 + 16*((4*s + g) ^ lsw));
            aq[0] = __builtin_amdgcn_mfma_f32_16x16x32_bf16(a_q[0][s], b, aq[0], 0,0,0);
            aq[1] = __builtin_amdgcn_mfma_f32_16x16x32_bf16(a_q[1][s], b, aq[1], 0,0,0);
        }
#pragma unroll
        for (int rt = 0; rt < 2; ++rt)
#pragma unroll
            for (int v = 0; v < 4; ++v) {
                float q2 = (aq[rt][v] + bqv[rt][v]) * LOG2E;
                float sg = __builtin_amdgcn_rcpf(1.f + __builtin_amdgcn_exp2f(-q2));
                lds_q[(32*w + 16*rt + 4*g + v)*68 + ct*16 + r] = f2bf(sg);
            }
    }

    // ---- cross-lane (s,p) reduce over the 16 r-lanes + partial write ----
#pragma unroll
    for (int rt = 0; rt < 2; ++rt)
#pragma unroll
        for (int v = 0; v < 4; ++v) {
            float s = s_run[rt][v], p = p_run[rt][v];
#pragma unroll
            for (int mask = 1; mask <= 8; mask <<= 1) {
                s += __shfl_xor(s, mask, 64);
                p += __shfl_xor(p, mask, 64);
            }
            if (r == 0) {
                int d = 32*w + 16*rt + 4*g + v;
                size_t idx = ((size_t)n*NCHUNK + ch)*CD + d;
                wsS[idx] = s;
                wsP[idx] = p;
            }
        }

    __syncthreads();
    // ---- store sig(Q) tile: [n][ch][d][64] bf16, coalesced ----
    {
        unsigned short* tile = wsq + ((size_t)(n*NCHUNK + ch)) * (CD*LCHUNK);
        const int col = tid & 7;
#pragma unroll
        for (int it = 0; it < 4; ++it) {
            int row = (tid >> 3) + 32*it;
            short8 val = *(const short8*)(lds_q + row*68 + 8*col);
            *(short8*)(tile + row*LCHUNK + 8*col) = val;
        }
    }
}

// ---------------- pass 2: combine partials -> pooled[n][d] ----------------
__global__ void aft_pass2(const float* __restrict__ wsS, const float* __restrict__ wsP,
                          float* __restrict__ pooled) {
    int n = blockIdx.x, d = threadIdx.x;
    float s = 0.f, p = 0.f;
    for (int b = 0; b < NCHUNK; ++b) {
        size_t idx = ((size_t)n*NCHUNK + b)*CD + d;
        s += wsS[idx];
        p += wsP[idx];
    }
    pooled[(size_t)n*CD + d] = p / s;
}

// ---------------- pass 3: out[n][d][l] = sig_q * pooled[n][d] ----------------
__global__ __launch_bounds__(256)
void aft_pass3(const unsigned short* __restrict__ wsq, const float* __restrict__ pooled,
               float* __restrict__ out) {
    __shared__ float lpool[CD];
    const int n = blockIdx.x >> 6;
    const int ch = blockIdx.x & 63;
    if (threadIdx.x < CD) lpool[threadIdx.x] = pooled[(size_t)n*CD + threadIdx.x];
    __syncthreads();
    const unsigned short* tile = wsq + ((size_t)(n*NCHUNK + ch)) * (CD*LCHUNK);
    const int l0 = ch * LCHUNK;
#pragma unroll
    for (int it = 0; it < 4; ++it) {
        int gi = threadIdx.x + 256*it;
        int row = gi >> 3, col = gi & 7;
        short8 v = *(const short8*)(tile + row*LCHUNK + 8*col);
        float pl = lpool[row];
        f32x4 o0, o1;
#pragma unroll
        for (int j = 0; j < 4; ++j) {
            o0[j] = bf2f((unsigned short)v[j]) * pl;
            o1[j] = bf2f((unsigned short)v[4+j]) * pl;
        }
        float* dst = out + ((size_t)n*CD + row)*LL + l0 + 8*col;
        *(f32x4*)dst = o0;
        *(f32x4*)(dst + 4) = o1;
    }
}

extern "C" void kernel_launch(void* const* d_in, const int* in_sizes, int n_in,
                              void* d_out, int out_size, void* d_ws, size_t ws_size,
                              hipStream_t stream) {
    const float* x  = (const float*)d_in[0];
    const float* Wq = (const float*)d_in[1];
    const float* bq = (const float*)d_in[2];
    const float* Wk = (const float*)d_in[3];
    const float* bk = (const float*)d_in[4];
    const float* Wv = (const float*)d_in[5];
    const float* bv = (const float*)d_in[6];
    float* out = (float*)d_out;
    char* ws = (char*)d_ws;
    unsigned short* wt = (unsigned short*)(ws + WT_OFF);
    float* wsS = (float*)(ws + WSS_OFF);
    float* wsP = (float*)(ws + WSP_OFF);
    float* pooled = (float*)(ws + POOL_OFF);
    unsigned short* wsq = (unsigned short*)(ws + WSQ_OFF);

    prep_wt<<<384, 128, 0, stream>>>(Wq, Wk, Wv, wt);
    aft_pass1<<<NB * NCHUNK, 256, 0, stream>>>(x, wt, bq, bk, bv, wsS, wsP, wsq);
    aft_pass2<<<NB, CD, 0, stream>>>(wsS, wsP, pooled);
    aft_pass3<<<NB * NCHUNK, 256, 0, stream>>>(wsq, pooled, out);
}